// Round 9
// baseline (440.029 us; speedup 1.0000x reference)
//
#include <hip/hip_runtime.h>
#include <hip/hip_bf16.h>
#include <math.h>

// ODE Euler solver — R12: W1 register-stationary.
// R11 (154us, verified): LDS pipe ~65% busy (1536 ds_read + 512KB DMA-write
// per block-step) is the largest consumer. W1's per-wave fragment slice is
// only 32KB = 128 VGPR -> hold it in registers for the whole chain:
//  * -256 weight ds_reads/step, -256KB DMA writes/step, -256KB L2 fetch/step
//  * MM1 phases become pure reg+zB compute (zero vmcnt waits)
//  * first vm wait of a step moves ~4k cyc after the epilogue stores ->
//    stores retire in the shadow -> uniform exact vmcnt(4), no relax hack
//  * b1 hoisted to regs (b1v) -> off the vmcnt ledger, no per-step loads
// Ring is now W2-only: 16 tiles/step (tile = chunk*8+kt), slot = tile&3.
// Reg budget: w1r 128 + acc 64 + b1v/b2v 24 + working ~40 ~= 250 <= 256 cap
// (__launch_bounds__(512,2)). Spill tripwire: FETCH >> 70MB.

using bf16x8 = __attribute__((ext_vector_type(8))) short;   // 8 bf16
using f32x4  = __attribute__((ext_vector_type(4))) float;   // 4 fp32 acc

constexpr int Bb = 64, Cc = 256, Tt = 64, Vv = 25, Hh = 512;
constexpr int TV = Tt * Vv;              // 1600
constexpr int MAXCH = Bb * (Tt - 1);     // 4032
constexpr int NGRID = 2496;              // >= worst-case n1+npair
constexpr int NTMAX = 4;                 // LDS stride in n-tiles

__device__ __forceinline__ short f2bf(float x) {
  union { float f; unsigned u; } v; v.f = x;
  unsigned r = v.u + 0x7FFFu + ((v.u >> 16) & 1u);
  return (short)(r >> 16);
}
__device__ __forceinline__ float fast_tanh(float x) {
  float e = __expf(2.f * x);
  return 1.f - 2.f * __builtin_amdgcn_rcpf(e + 1.f);
}
// lgkm-only barrier: LDS deps drained, global loads/stores stay in flight.
__device__ __forceinline__ void bar_lds() {
  asm volatile("s_waitcnt lgkmcnt(0)" ::: "memory");
  __builtin_amdgcn_s_barrier();
  asm volatile("" ::: "memory");
}
// 16B/lane global->LDS DMA. LDS dest = base + lane*16 (wave-uniform base).
__device__ __forceinline__ void gl2lds16(const short* g, short* l) {
  __builtin_amdgcn_global_load_lds(
      (const __attribute__((address_space(1))) void*)g,
      (__attribute__((address_space(3))) void*)l, 16, 0, 0);
}

// ---- fused prepack (blocks 0..1023) + plan (block 1024) ----
// A-frag (16x16x32): lane holds A[m=lane&15][k=(lane>>4)*8+j].
// a1p: A=W1^T (M=H: 32 mt, K=C: 8 kt):  idx ((kt*32+mt)*64+lane)*8+j
// a2p: A=W2^T (M=C: 16 mt, K=H: 16 kt): idx ((kt*16+mt)*64+lane)*8+j
__global__ void prep_kernel(const float* __restrict__ W1,
                            const float* __restrict__ W2,
                            const float* __restrict__ tf,
                            short* __restrict__ a1p,
                            short* __restrict__ a2p,
                            int* __restrict__ sorted,
                            int* __restrict__ hdr) {
  if (blockIdx.x < 1024) {
    int idx = blockIdx.x * 256 + threadIdx.x;
    if (idx < 131072) {
      int j = idx & 7, lane = (idx >> 3) & 63, mt = (idx >> 9) & 31, kt = idx >> 14;
      int h = mt * 16 + (lane & 15);
      int c = kt * 32 + (lane >> 4) * 8 + j;
      a1p[idx] = f2bf(W1[c * Hh + h]);
    } else {
      int i2 = idx - 131072;
      int j = i2 & 7, lane = (i2 >> 3) & 63, mt = (i2 >> 9) & 15, kt = i2 >> 13;
      int cm = mt * 16 + (lane & 15);
      int hk = kt * 32 + (lane >> 4) * 8 + j;
      a2p[i2] = f2bf(W2[hk * Cc + cm]);
    }
    return;
  }
  __shared__ int cnt[64];
  __shared__ int ofs[64];
  int tid = threadIdx.x;
  if (tid < 64) cnt[tid] = 0;
  for (int i = tid; i < MAXCH; i += 256) sorted[i] = 0;
  __syncthreads();
  if (tid < Bb) {
    int b = tid, prev = 0;
    for (int t = 1; t <= 62; t++)
      if (tf[t * Bb + b] >= 0.5f) { atomicAdd(&cnt[t - prev], 1); prev = t; }
    atomicAdd(&cnt[63 - prev], 1);
  }
  __syncthreads();
  if (tid == 0) {
    int acc = 0;
    for (int l = 63; l >= 1; l--) { ofs[l] = acc; acc += cnt[l]; }
    int n1 = 0;
    for (int l = 5; l <= 63; l++) n1 += cnt[l];
    hdr[0] = n1;                      // solos (len>=5)
    hdr[1] = (acc - n1 + 1) >> 1;     // pairs covering the rest
    hdr[2] = acc; hdr[3] = 0;
  }
  __syncthreads();
  if (tid < Bb) {
    int b = tid, prev = 0;
    for (int t = 1; t <= 62; t++) {
      if (tf[t * Bb + b] >= 0.5f) {
        int len = t - prev;
        int p = atomicAdd(&ofs[len], 1);
        sorted[p] = b | (prev << 6) | (len << 12);
        prev = t;
      }
    }
    int len = 63 - prev;
    int p = atomicAdd(&ofs[len], 1);
    sorted[p] = b | (prev << 6) | (len << 12);
  }
}

// LDS B-frag order (stride NTMAX):
// elem(k,n) at ((ktile*NTMAX + nt)*64 + (n&15) + 16*((k&31)>>3))*8 + (k&7)
template<int NCH>
__device__ __forceinline__ void run_group(
    int start,
    const float* __restrict__ hsrc, const float* __restrict__ b1,
    const float* __restrict__ b2,   const short* __restrict__ a1p,
    const short* __restrict__ a2p,  const int* __restrict__ sorted,
    float* __restrict__ out, short* __restrict__ zB, short* __restrict__ uB,
    short* __restrict__ wA) {
  constexpr int NTA = NCH * 2;                  // n-tiles (16 cols each)
  const int tid  = threadIdx.x;
  const int lane = tid & 63;
  const int w    = tid >> 6;                    // 0..7
  const int m16  = lane & 15;
  const int quad = lane >> 4;
  short* wv = wA + w * 4096;                    // 4 slots x 2KB per wave

  int meta[NCH], len[NCH], sbase[NCH], t0s[NCH];
  #pragma unroll
  for (int j = 0; j < NCH; j++) {
    meta[j]  = sorted[start + j];               // block-uniform -> s_load
    len[j]   = (meta[j] >> 12) & 63;
    t0s[j]   = (meta[j] >> 6) & 63;
    sbase[j] = (meta[j] & 63) * Cc * TV + t0s[j] * Vv;
  }
  const int maxlen = len[0];                    // sorted desc

  // ---- W1 register-stationary: per-wave slice = 128 VGPR, loaded once ----
  bf16x8 w1r[2][8][2];                          // [chunk][kt][mt_i]
  #pragma unroll
  for (int ch = 0; ch < 2; ch++)
    #pragma unroll
    for (int kt = 0; kt < 8; kt++) {
      const short* ab = a1p + ((kt * 32 + ch * 16 + w * 2) * 64 + lane) * 8;
      w1r[ch][kt][0] = *(const bf16x8*)ab;
      w1r[ch][kt][1] = *(const bf16x8*)(ab + 512);
    }

  f32x4 acc2[2][NTA];                           // fp32 master state

  // ---- init: z0 = h[b,:,t0,:]; write zB in B-frag order ----
  #pragma unroll
  for (int i = 0; i < 2; i++) {
    const int cbase = (w * 2 + i) * 16 + quad * 4;    // 0..255, mult of 4
    const int ktz = cbase >> 5;
    const int gq  = (cbase >> 3) & 3;
    const int j0  = cbase & 7;
    #pragma unroll
    for (int nt = 0; nt < NTA; nt++) {
      const int j  = nt >> 1;
      const int v  = (nt & 1) * 16 + m16;
      const bool valid = (len[j] > 0) && (v < Vv);
      const int hb = sbase[j] + cbase * TV + v;
      f32x4 z;
      #pragma unroll
      for (int r = 0; r < 4; r++)
        z[r] = valid ? __builtin_nontemporal_load(&hsrc[hb + r * TV]) : 0.f;
      acc2[i][nt] = z;
      short4 zh;
      zh.x = f2bf(z[0]); zh.y = f2bf(z[1]); zh.z = f2bf(z[2]); zh.w = f2bf(z[3]);
      *(short4*)&zB[((ktz * NTMAX + nt) * 64 + m16 + 16 * gq) * 8 + j0] = zh;
      if (valid && t0s[j] == 0) {
        #pragma unroll
        for (int r = 0; r < 4; r++) out[hb + r * TV] = z[r];
      }
    }
  }

  // W2 tile stream: 16 tiles/step (tile = chunk*8+kt), 2KB/tile/wave,
  // 4-slot ring (slot = tile&3), prefetch depth 2, addresses step-invariant.
  auto ISSUE = [&](int tile) {
    const short* gp = a2p + ((tile * 16 + w * 2) * 64 + lane) * 8;
    short* lp = wv + (tile & 3) * 1024;
    gl2lds16(gp, lp);             // mt0 fragment (1KB)
    gl2lds16(gp + 512, lp + 512); // mt1 fragment (1KB)
  };

  // prologue: prime the ring
  ISSUE(0);
  ISSUE(1);
  bar_lds();                     // zB visible (lgkm only; DMA stays in flight)

  // step-invariant biases in registers (also: off the vmcnt ledger)
  f32x4 b2v[2];
  f32x4 b1v[2][2];               // [chunk][i]
  #pragma unroll
  for (int i = 0; i < 2; i++) {
    const float4 t = *(const float4*)(b2 + (w * 2 + i) * 16 + quad * 4);
    b2v[i] = (f32x4){t.x, t.y, t.z, t.w};
    #pragma unroll
    for (int ch = 0; ch < 2; ch++) {
      const float4 u = *(const float4*)(b1 + ch * 256 + (w * 2 + i) * 16 + quad * 4);
      b1v[ch][i] = (f32x4){u.x, u.y, u.z, u.w};
    }
  }

  for (int s = 0; s < maxlen; s++) {
    // MM1 chunk from REGISTERS: pure reg+zB compute, zero vm waits.
    auto MM1R = [&](int ch, f32x4 (&a1)[2][NTA]) {
      #pragma unroll
      for (int kt = 0; kt < 8; kt++) {
        #pragma unroll
        for (int nt = 0; nt < NTA; nt++) {
          bf16x8 bz = *(const bf16x8*)&zB[((kt * NTMAX + nt) * 64 + lane) * 8];
          a1[0][nt] = __builtin_amdgcn_mfma_f32_16x16x32_bf16(w1r[ch][kt][0], bz, a1[0][nt], 0, 0, 0);
          a1[1][nt] = __builtin_amdgcn_mfma_f32_16x16x32_bf16(w1r[ch][kt][1], bz, a1[1][nt], 0, 0, 0);
        }
      }
    };
    // MM2 chunk from the W2 ring: tiles ch*8..ch*8+7, exact vmcnt(4).
    auto MM2R = [&](int ch) {
      #pragma unroll
      for (int kt = 0; kt < 8; kt++) {
        const int tile = ch * 8 + kt;
        ISSUE((tile + 2) & 15);   // unconditional: ledger exact every iter
        asm volatile("s_waitcnt vmcnt(4)" ::: "memory");  // tile landed
        const short* wp = wv + (tile & 3) * 1024 + lane * 8;
        bf16x8 af0 = *(const bf16x8*)wp;
        bf16x8 af1 = *(const bf16x8*)(wp + 512);
        #pragma unroll
        for (int nt = 0; nt < NTA; nt++) {
          bf16x8 bu = *(const bf16x8*)&uB[((kt * NTMAX + nt) * 64 + lane) * 8];
          acc2[0][nt] = __builtin_amdgcn_mfma_f32_16x16x32_bf16(af0, bu, acc2[0][nt], 0, 0, 0);
          acc2[1][nt] = __builtin_amdgcn_mfma_f32_16x16x32_bf16(af1, bu, acc2[1][nt], 0, 0, 0);
        }
      }
    };
    auto UEPI = [&](int ch, f32x4 (&a1)[2][NTA]) {
      #pragma unroll
      for (int i = 0; i < 2; i++) {
        const int hl  = (w * 2 + i) * 16 + quad * 4;   // chunk-local h
        const int ktl = hl >> 5;
        const int gq  = (hl >> 3) & 3;
        const int j0  = hl & 7;
        #pragma unroll
        for (int nt = 0; nt < NTA; nt++) {
          short4 up;
          up.x = f2bf(fast_tanh(a1[i][nt][0] + b1v[ch][i][0]));
          up.y = f2bf(fast_tanh(a1[i][nt][1] + b1v[ch][i][1]));
          up.z = f2bf(fast_tanh(a1[i][nt][2] + b1v[ch][i][2]));
          up.w = f2bf(fast_tanh(a1[i][nt][3] + b1v[ch][i][3]));
          *(short4*)&uB[((ktl * NTMAX + nt) * 64 + m16 + 16 * gq) * 8 + j0] = up;
        }
      }
    };

    #pragma unroll
    for (int i = 0; i < 2; i++)
      #pragma unroll
      for (int nt = 0; nt < NTA; nt++) {
        acc2[i][nt][0] += b2v[i][0]; acc2[i][nt][1] += b2v[i][1];
        acc2[i][nt][2] += b2v[i][2]; acc2[i][nt][3] += b2v[i][3];
      }

    f32x4 acc1[2][NTA];
    #pragma unroll
    for (int i = 0; i < 2; i++)
      #pragma unroll
      for (int nt = 0; nt < NTA; nt++) acc1[i][nt] = (f32x4){0.f, 0.f, 0.f, 0.f};
    MM1R(0, acc1);             // W1 from regs, zB from LDS
    UEPI(0, acc1);
    bar_lds();                 // A: uB(c0) visible
    MM2R(0);                   // ring tiles 0..7
    #pragma unroll
    for (int i = 0; i < 2; i++)
      #pragma unroll
      for (int nt = 0; nt < NTA; nt++) acc1[i][nt] = (f32x4){0.f, 0.f, 0.f, 0.f};
    MM1R(1, acc1);             // overlaps MM2R(0) region (indep of uB)
    bar_lds();                 // B: all uB(c0) reads done
    UEPI(1, acc1);
    bar_lds();                 // C: uB(c1) visible
    MM2R(1);                   // ring tiles 8..15
    // ---- z epilogue: refresh zB, store alive cols (plain L2 stores) ----
    #pragma unroll
    for (int i = 0; i < 2; i++) {
      const int cbase = (w * 2 + i) * 16 + quad * 4;
      const int ktz = cbase >> 5;
      const int gq  = (cbase >> 3) & 3;
      const int j0  = cbase & 7;
      #pragma unroll
      for (int nt = 0; nt < NTA; nt++) {
        short4 zh;
        zh.x = f2bf(acc2[i][nt][0]); zh.y = f2bf(acc2[i][nt][1]);
        zh.z = f2bf(acc2[i][nt][2]); zh.w = f2bf(acc2[i][nt][3]);
        *(short4*)&zB[((ktz * NTMAX + nt) * 64 + m16 + 16 * gq) * 8 + j0] = zh;
        const int v = (nt & 1) * 16 + m16;
        if (v < Vv && s < len[nt >> 1]) {
          const int o = sbase[nt >> 1] + cbase * TV + v + (s + 1) * Vv;
          out[o]          = acc2[i][nt][0];
          out[o + TV]     = acc2[i][nt][1];
          out[o + 2 * TV] = acc2[i][nt][2];
          out[o + 3 * TV] = acc2[i][nt][3];
        }
      }
    }
    bar_lds();                 // D: zB ready for next step
  }
}

__global__ __launch_bounds__(512, 2) void group_kernel(
    const float* __restrict__ hsrc, const float* __restrict__ b1,
    const float* __restrict__ b2,   const short* __restrict__ a1p,
    const short* __restrict__ a2p,  const int* __restrict__ sorted,
    const int* __restrict__ hdr,    float* __restrict__ out) {
  __shared__ __align__(16) short zB[8 * NTMAX * 64 * 8];   // 32 KB
  __shared__ __align__(16) short uB[8 * NTMAX * 64 * 8];   // 32 KB
  __shared__ __align__(16) short wA[8 * 4 * 1024];         // 64 KB W2 ring

  const int n1 = hdr[0], npair = hdr[1];
  const int bi = blockIdx.x;
  if (bi < n1) {
    run_group<1>(bi, hsrc, b1, b2, a1p, a2p, sorted, out, zB, uB, wA);
  } else if (bi < n1 + npair) {
    run_group<2>(n1 + (bi - n1) * 2, hsrc, b1, b2, a1p, a2p, sorted, out, zB, uB, wA);
  }
}

extern "C" void kernel_launch(void* const* d_in, const int* in_sizes, int n_in,
                              void* d_out, int out_size, void* d_ws, size_t ws_size,
                              hipStream_t stream) {
  const float* h_ptr = (const float*)d_in[0];
  const float* W1    = (const float*)d_in[1];
  const float* b1    = (const float*)d_in[2];
  const float* W2    = (const float*)d_in[3];
  const float* b2    = (const float*)d_in[4];
  const float* tf    = (const float*)d_in[5];
  float* out = (float*)d_out;

  short* a1p  = (short*)d_ws;            // 256 KB
  short* a2p  = a1p + 131072;            // 256 KB
  int* sorted = (int*)(a2p + 131072);    // 16 KB
  int* hdr    = sorted + MAXCH;          // 16 B

  prep_kernel<<<1025, 256, 0, stream>>>(W1, W2, tf, a1p, a2p, sorted, hdr);
  group_kernel<<<NGRID, 512, 0, stream>>>(h_ptr, b1, b2, a1p, a2p, sorted, hdr, out);
}